// Round 6
// baseline (871.289 us; speedup 1.0000x reference)
//
#include <hip/hip_runtime.h>

// VQ-VAE quantizer: h (256,512,32) fp32, embeddings (1024,32) fp32.
// d_out (fp32): quantized_st [4194304] | indices [131072] | loss [131072]
//
// R6 strategy: bf16-MFMA as a CERTIFIED FILTER + exact fp32 recheck.
//  - approx s(c) = e2[c] - 2*dot_bf16(f,e) via mfma_f32_16x16x32_bf16 (fp32 acc)
//  - |s_approx - s_exact| <= 2*2^-8*Sigma|f_k||e_k| + eps <= 2.0e-3  (|f|<=8, |e|<=2^-10)
//  - sweep1: per-row approx min; sweep2: recheck every c with s <= min + T (T=6e-3)
//    using the BIT-EXACT numpy chain (pairwise ||f||^2, sequential fmaf dot,
//    fl(fl(f2+e2)-2dot)); u64 key (enc(d)<<32|c) min == first-occurrence argmin.
//  - fully fused: one prep kernel (e2 + bf16 B-frag table) + one scan kernel.
// Perf history: R3 270us (occ-bound) -> R4 240 (sgpr-pressure copies) ->
// R5 193 (scan 126us, ~1.4x of the 55us fp32-VALU floor) -> R6: switch engine.

#define EMB_N 1024
#define DIM 32
#define NVEC (256 * 512)
#define NTILES (EMB_N / 16)   // 64 candidate tiles
#define THRESH 6.0e-3f

typedef unsigned long long u64;
typedef unsigned int u32;
typedef __attribute__((ext_vector_type(8))) short bf16x8;
typedef __attribute__((ext_vector_type(4))) float f32x4;

__device__ __forceinline__ u32 enc_f32(float x) {
    u32 u = __float_as_uint(x);
    return (u & 0x80000000u) ? ~u : (u | 0x80000000u);  // monotone order-preserving
}
__device__ __forceinline__ unsigned short f2bf(float f) {  // RNE fp32->bf16
    u32 u = __float_as_uint(f);
    return (unsigned short)((u + 0x7FFFu + ((u >> 16) & 1u)) >> 16);
}
__device__ __forceinline__ u64 shfl_u64(u64 x, int src) {
    int lo = __shfl((int)(u32)x, src);
    int hi = __shfl((int)(x >> 32), src);
    return ((u64)(u32)hi << 32) | (u32)lo;
}
__device__ __forceinline__ u64 shflx_u64(u64 x, int m) {
    int lo = __shfl_xor((int)(u32)x, m);
    int hi = __shfl_xor((int)(x >> 32), m);
    return ((u64)(u32)hi << 32) | (u32)lo;
}

// numpy pairwise ||x||^2 for n=32: 8 accumulators stride 8, fixed combine tree
__device__ __forceinline__ float norm2_np(const float* fr) {
    float sq[DIM];
#pragma unroll
    for (int i = 0; i < DIM; ++i) sq[i] = fr[i] * fr[i];
    float r[8];
#pragma unroll
    for (int j = 0; j < 8; ++j)
        r[j] = ((sq[j] + sq[j + 8]) + sq[j + 16]) + sq[j + 24];
    return ((r[0] + r[1]) + (r[2] + r[3])) + ((r[4] + r[5]) + (r[6] + r[7]));
}

// ---- prep: e2 (numpy order) + bf16 B-fragment table in MFMA lane layout ----
// frag element (nt, lane, j) = bf16( emb[nt*16 + (lane&15)][ (lane>>4)*8 + j ] )
__global__ __launch_bounds__(256) void prep_kernel(
    const float* __restrict__ emb,
    float* __restrict__ e2,
    unsigned short* __restrict__ bfrag)
{
#pragma clang fp contract(off)
    const int t = blockIdx.x * 256 + threadIdx.x;    // 0..4095
    const int l = t & 63;
    const int row = ((t >> 6) << 4) + (l & 15);
    const int k0 = (l >> 4) * 8;
    const float* ep = emb + (size_t)row * DIM + k0;
    unsigned short* dst = bfrag + (size_t)t * 8;
#pragma unroll
    for (int j = 0; j < 8; ++j) dst[j] = f2bf(ep[j]);

    if (t < EMB_N) {
        const float* e = emb + (size_t)t * DIM;
        float tmp[DIM];
#pragma unroll
        for (int i = 0; i < DIM; ++i) tmp[i] = e[i];
        e2[t] = norm2_np(tmp);
    }
}

// ---- fused scan: 1 wave = 32 rows (2 MFMA row-tiles); sweep1 min, sweep2
//      filtered exact recheck, quad-reduce, epilogue writes ----
__global__ __launch_bounds__(256) void vq_mfma(
    const float* __restrict__ h,
    const float* __restrict__ emb,
    const float* __restrict__ e2,
    const unsigned short* __restrict__ bfrag,
    float* __restrict__ out_q,
    float* __restrict__ out_idx,
    float* __restrict__ out_loss)
{
#pragma clang fp contract(off)
    const int wid   = (blockIdx.x * 256 + threadIdx.x) >> 6;  // 0..4095
    const int lane  = threadIdx.x & 63;
    const int col16 = lane & 15;
    const int quad  = lane >> 4;
    const size_t row0 = (size_t)wid * 32;

    // A-fragments for the 2 row-tiles (convert on the fly; layout A[m=lane&15][k=quad*8+j])
    bf16x8 afr0, afr1;
    {
        const float* ap = h + (row0 + col16) * DIM + quad * 8;
        float4 x = *(const float4*)ap, y = *(const float4*)(ap + 4);
        afr0[0]=(short)f2bf(x.x); afr0[1]=(short)f2bf(x.y); afr0[2]=(short)f2bf(x.z); afr0[3]=(short)f2bf(x.w);
        afr0[4]=(short)f2bf(y.x); afr0[5]=(short)f2bf(y.y); afr0[6]=(short)f2bf(y.z); afr0[7]=(short)f2bf(y.w);
        const float* bp = ap + 16 * DIM;
        float4 u = *(const float4*)bp, v = *(const float4*)(bp + 4);
        afr1[0]=(short)f2bf(u.x); afr1[1]=(short)f2bf(u.y); afr1[2]=(short)f2bf(u.z); afr1[3]=(short)f2bf(u.w);
        afr1[4]=(short)f2bf(v.x); afr1[5]=(short)f2bf(v.y); afr1[6]=(short)f2bf(v.z); afr1[7]=(short)f2bf(v.w);
    }

    // exact f2 (numpy pairwise) for all 32 rows: lane i and i+32 compute local row i&31,
    // then each lane shfl-gathers the 8 rows it may recheck (all lanes active).
    float f2mine;
    {
        const float* fp = h + (row0 + (lane & 31)) * DIM;
        float t[DIM];
#pragma unroll
        for (int i = 0; i < DIM; i += 4) {
            float4 x = *(const float4*)(fp + i);
            t[i] = x.x; t[i + 1] = x.y; t[i + 2] = x.z; t[i + 3] = x.w;
        }
        f2mine = norm2_np(t);
    }
    float f2pre[8];
#pragma unroll
    for (int i = 0; i < 8; ++i) {
        int rt = i >> 2, r = i & 3;
        f2pre[i] = __shfl(f2mine, rt * 16 + quad * 4 + r);  // local row of (rt, quad, r)
    }

    const f32x4 zacc = {0.f, 0.f, 0.f, 0.f};

    // ---- sweep 1: approx min per (rt, reg) slot ----
    float bs[8];
#pragma unroll
    for (int i = 0; i < 8; ++i) bs[i] = 3.4e38f;
#pragma unroll 1
    for (int nt = 0; nt < NTILES; ++nt) {
        bf16x8 b = *(const bf16x8*)(bfrag + nt * 512 + lane * 8);
        f32x4 d0 = __builtin_amdgcn_mfma_f32_16x16x32_bf16(afr0, b, zacc, 0, 0, 0);
        f32x4 d1 = __builtin_amdgcn_mfma_f32_16x16x32_bf16(afr1, b, zacc, 0, 0, 0);
        float e2c = e2[nt * 16 + col16];
#pragma unroll
        for (int r = 0; r < 4; ++r) {
            bs[r]     = fminf(bs[r],     __builtin_fmaf(-2.f, d0[r], e2c));
            bs[4 + r] = fminf(bs[4 + r], __builtin_fmaf(-2.f, d1[r], e2c));
        }
    }
    // quad-reduce mins across the 16 column-lanes
#pragma unroll
    for (int m = 1; m < 16; m <<= 1)
#pragma unroll
        for (int i = 0; i < 8; ++i) bs[i] = fminf(bs[i], __shfl_xor(bs[i], m));
    float thr[8];
#pragma unroll
    for (int i = 0; i < 8; ++i) thr[i] = bs[i] + THRESH;

    // ---- sweep 2: recompute (bit-identical), exact-recheck qualifiers ----
    u64 kb[8];
#pragma unroll
    for (int i = 0; i < 8; ++i) kb[i] = ~0ull;
#pragma unroll 1
    for (int nt = 0; nt < NTILES; ++nt) {
        bf16x8 b = *(const bf16x8*)(bfrag + nt * 512 + lane * 8);
        f32x4 d0 = __builtin_amdgcn_mfma_f32_16x16x32_bf16(afr0, b, zacc, 0, 0, 0);
        f32x4 d1 = __builtin_amdgcn_mfma_f32_16x16x32_bf16(afr1, b, zacc, 0, 0, 0);
        float e2c = e2[nt * 16 + col16];
        const int cc = nt * 16 + col16;
#pragma unroll
        for (int i = 0; i < 8; ++i) {
            const int rt = i >> 2, r = i & 3;
            float s = __builtin_fmaf(-2.f, (rt ? d1[r] : d0[r]), e2c);
            bool q = (s <= thr[i]);
            if (__ballot(q)) {
                if (q) {
                    const int row = (int)row0 + rt * 16 + quad * 4 + r;
                    const float* fp = h + (size_t)row * DIM;
                    float fr[DIM];
#pragma unroll
                    for (int k = 0; k < DIM; k += 4) {
                        float4 x = *(const float4*)(fp + k);
                        fr[k] = x.x; fr[k + 1] = x.y; fr[k + 2] = x.z; fr[k + 3] = x.w;
                    }
                    const float* ep = emb + (size_t)cc * DIM;
                    float a = 0.f;
#pragma unroll
                    for (int k = 0; k < DIM; ++k) a = __builtin_fmaf(fr[k], ep[k], a);  // BLAS chain
                    float dd = (f2pre[i] + e2[cc]) - (2.0f * a);  // exact numpy formula
                    u64 key = ((u64)enc_f32(dd) << 32) | (u32)cc;
                    if (key < kb[i]) kb[i] = key;
                }
            }
        }
    }
    // quad-reduce exact keys (min == first-occurrence argmin over S)
#pragma unroll
    for (int m = 1; m < 16; m <<= 1)
#pragma unroll
        for (int i = 0; i < 8; ++i) {
            u64 o = shflx_u64(kb[i], m);
            if (o < kb[i]) kb[i] = o;
        }

    // distribute keys: lane (0..31) owns output row row0 + rt*16 + rloc
    const int rt_o = (lane >> 4) & 1, rloc = lane & 15;
    const int qsrc = rloc >> 2, want = rt_o * 4 + (rloc & 3);
    u64 key = 0;
#pragma unroll
    for (int i = 0; i < 8; ++i) {
        u64 tv = shfl_u64(kb[i], qsrc * 16);  // all lanes active for shfl
        if (i == want) key = tv;
    }

    if (lane < 32) {
        const int row  = (int)row0 + rt_o * 16 + rloc;
        const int bidx = (int)(key & 0xFFFFFFFFu);
        const float* f = h + (size_t)row * DIM;
        const float* qv = emb + (size_t)bidx * DIM;
        float ps = 0.f;
#pragma unroll
        for (int i = 0; i < DIM; i += 4) {
            float4 fx = *(const float4*)(f + i);
            float4 qx; qx.x = qv[i]; qx.y = qv[i+1]; qx.z = qv[i+2]; qx.w = qv[i+3];
            float dx = qx.x - fx.x, dy = qx.y - fx.y, dz = qx.z - fx.z, dw = qx.w - fx.w;
            ps += dx * dx; ps += dy * dy; ps += dz * dz; ps += dw * dw;
            float4 o;
            o.x = fx.x + (qx.x - fx.x);
            o.y = fx.y + (qx.y - fx.y);
            o.z = fx.z + (qx.z - fx.z);
            o.w = fx.w + (qx.w - fx.w);
            *(float4*)(out_q + (size_t)row * DIM + i) = o;
        }
        float m = ps * (1.0f / DIM);
        out_idx[row]  = (float)bidx;
        out_loss[row] = m * 0.1f + m * 0.1f;
    }
}

// ---------- fallback (R3-style single kernel) if workspace is too small ----------
__global__ void e2_kernel(const float* __restrict__ emb, float* __restrict__ e2) {
#pragma clang fp contract(off)
    int c = blockIdx.x * blockDim.x + threadIdx.x;
    if (c >= EMB_N) return;
    const float* e = emb + (size_t)c * DIM;
    float tmp[DIM];
#pragma unroll
    for (int i = 0; i < DIM; ++i) tmp[i] = e[i];
    e2[c] = norm2_np(tmp);
}

__global__ __launch_bounds__(256) void vq_kernel(
    const float* __restrict__ h, const float* __restrict__ emb,
    const float* __restrict__ e2, float* __restrict__ out_q,
    float* __restrict__ out_idx, float* __restrict__ out_loss)
{
#pragma clang fp contract(off)
    const int v = blockIdx.x * blockDim.x + threadIdx.x;
    const float* f = h + (size_t)v * DIM;
    float fr[DIM];
#pragma unroll
    for (int i = 0; i < DIM; i += 4) {
        float4 x = *(const float4*)(f + i);
        fr[i] = x.x; fr[i + 1] = x.y; fr[i + 2] = x.z; fr[i + 3] = x.w;
    }
    const float f2 = norm2_np(fr);
    float best = 3.4e38f; int bidx = 0;
#pragma unroll 1
    for (int c = 0; c < EMB_N; ++c) {
        const float* e = emb + (size_t)c * DIM;
        float a0 = 0.f;
#pragma unroll
        for (int k = 0; k < DIM; ++k) a0 = __builtin_fmaf(fr[k], e[k], a0);
        float d0 = (f2 + e2[c]) - (2.0f * a0);
        if (d0 < best) { best = d0; bidx = c; }
    }
    const float* q = emb + (size_t)bidx * DIM;
    float ps = 0.f;
#pragma unroll
    for (int i = 0; i < DIM; i += 4) {
        float4 fx; fx.x = fr[i]; fx.y = fr[i+1]; fx.z = fr[i+2]; fx.w = fr[i+3];
        float4 qx; qx.x = q[i]; qx.y = q[i+1]; qx.z = q[i+2]; qx.w = q[i+3];
        float dx = qx.x - fx.x, dy = qx.y - fx.y, dz = qx.z - fx.z, dw = qx.w - fx.w;
        ps += dx * dx; ps += dy * dy; ps += dz * dz; ps += dw * dw;
        float4 o;
        o.x = fx.x + (qx.x - fx.x); o.y = fx.y + (qx.y - fx.y);
        o.z = fx.z + (qx.z - fx.z); o.w = fx.w + (qx.w - fx.w);
        *(float4*)(out_q + (size_t)v * DIM + i) = o;
    }
    float m = ps * (1.0f / DIM);
    out_idx[v]  = (float)bidx;
    out_loss[v] = m * 0.1f + m * 0.1f;
}

extern "C" void kernel_launch(void* const* d_in, const int* in_sizes, int n_in,
                              void* d_out, int out_size, void* d_ws, size_t ws_size,
                              hipStream_t stream) {
    const float* h   = (const float*)d_in[0];
    const float* emb = (const float*)d_in[1];
    float* out = (float*)d_out;
    float* out_q    = out;                               // 4194304
    float* out_idx  = out + (size_t)NVEC * DIM;          // 131072
    float* out_loss = out + (size_t)NVEC * DIM + NVEC;   // 131072

    float* e2 = (float*)d_ws;                                   // 4 KB
    unsigned short* bfrag = (unsigned short*)((char*)d_ws + 4096);  // 64 KB
    const size_t need = 4096 + (size_t)NTILES * 512 * sizeof(unsigned short);

    if (ws_size >= need) {
        prep_kernel<<<16, 256, 0, stream>>>(emb, e2, bfrag);
        vq_mfma<<<1024, 256, 0, stream>>>(h, emb, e2, bfrag, out_q, out_idx, out_loss);
    } else {
        e2_kernel<<<EMB_N / 256, 256, 0, stream>>>(emb, e2);
        vq_kernel<<<NVEC / 256, 256, 0, stream>>>(h, emb, e2, out_q, out_idx, out_loss);
    }
}

// Round 7
// 566.150 us; speedup vs baseline: 1.5390x; 1.5390x over previous
//
#include <hip/hip_runtime.h>

// VQ-VAE quantizer: h (256,512,32) fp32, embeddings (1024,32) fp32.
// d_out (fp32): quantized_st [4194304] | indices [131072] | loss [131072]
//
// R7: bf16-MFMA certified filter, DECOUPLED into dense kernels (R6's fused
// divergent recheck was latency-serialized garbage: 871us).
//   K1 prep:    e2 (numpy pairwise) + bf16 B-frag table (MFMA lane layout)
//   K2 thresh:  MFMA sweep -> thr[row] = approx_min + T, cnt[row] = 0
//   K3 filter:  MFMA sweep -> qualifying (row,c): cand[row][slot++] = c
//   K4 exact:   per row: bit-exact numpy recheck of listed candidates
//               (u64 key enc(d)<<32|c -> first-occurrence argmin) + epilogue
// Certification: |s_bf16 - s_exact| <= 2*2^-8*Sum|f||e| + eps <= E=2e-3
// (|f|<=8 w.p. 1-5e-9, |e|<=2^-10). T=3E=6e-3 >= 2E guarantees the exact
// argmin and all its exact ties qualify. cnt==0 or >8 -> full exact scan.
// Perf history: R3 270 -> R4 240 -> R5 193 -> R6 871 (fused filter, FAILED)

#define EMB_N 1024
#define DIM 32
#define NVEC (256 * 512)
#define NTILES (EMB_N / 16)
#define THRESH 6.0e-3f
#define MAXC 8

typedef unsigned long long u64;
typedef unsigned int u32;
typedef __attribute__((ext_vector_type(8))) short bf16x8;
typedef __attribute__((ext_vector_type(4))) float f32x4;

__device__ __forceinline__ u32 enc_f32(float x) {
    u32 u = __float_as_uint(x);
    return (u & 0x80000000u) ? ~u : (u | 0x80000000u);  // monotone order-preserving
}
__device__ __forceinline__ unsigned short f2bf(float f) {  // RNE fp32->bf16
    u32 u = __float_as_uint(f);
    return (unsigned short)((u + 0x7FFFu + ((u >> 16) & 1u)) >> 16);
}

// numpy pairwise ||x||^2, n=32: 8 accumulators stride 8, fixed combine tree
__device__ __forceinline__ float norm2_np(const float* fr) {
    float sq[DIM];
#pragma unroll
    for (int i = 0; i < DIM; ++i) sq[i] = fr[i] * fr[i];
    float r[8];
#pragma unroll
    for (int j = 0; j < 8; ++j)
        r[j] = ((sq[j] + sq[j + 8]) + sq[j + 16]) + sq[j + 24];
    return ((r[0] + r[1]) + (r[2] + r[3])) + ((r[4] + r[5]) + (r[6] + r[7]));
}

// ---- K1: e2 + bf16 B-fragment table. frag(nt,lane,j) = bf16(emb[nt*16+(lane&15)][(lane>>4)*8+j])
__global__ __launch_bounds__(256) void prep_kernel(
    const float* __restrict__ emb, float* __restrict__ e2,
    unsigned short* __restrict__ bfrag)
{
#pragma clang fp contract(off)
    const int t = blockIdx.x * 256 + threadIdx.x;    // 0..4095
    const int l = t & 63;
    const int row = ((t >> 6) << 4) + (l & 15);
    const int k0 = (l >> 4) * 8;
    const float* ep = emb + (size_t)row * DIM + k0;
    unsigned short* dst = bfrag + (size_t)t * 8;
#pragma unroll
    for (int j = 0; j < 8; ++j) dst[j] = f2bf(ep[j]);
    if (t < EMB_N) {
        const float* e = emb + (size_t)t * DIM;
        float tmp[DIM];
#pragma unroll
        for (int i = 0; i < DIM; ++i) tmp[i] = e[i];
        e2[t] = norm2_np(tmp);
    }
}

// ---- K2: approx min per row -> thr[], cnt[]=0.  1 wave = 16 rows. ----
__global__ __launch_bounds__(256) void vq_thresh(
    const float* __restrict__ h,
    const float* __restrict__ e2,
    const unsigned short* __restrict__ bfrag,
    float* __restrict__ thr, u32* __restrict__ cnt)
{
    const int wid   = (blockIdx.x * 256 + threadIdx.x) >> 6;  // 0..8191
    const int lane  = threadIdx.x & 63;
    const int col16 = lane & 15;
    const int quad  = lane >> 4;
    const size_t row0 = (size_t)wid * 16;

    bf16x8 afr;
    {
        const float* ap = h + (row0 + col16) * DIM + quad * 8;
        float4 x = *(const float4*)ap, y = *(const float4*)(ap + 4);
        afr[0]=(short)f2bf(x.x); afr[1]=(short)f2bf(x.y); afr[2]=(short)f2bf(x.z); afr[3]=(short)f2bf(x.w);
        afr[4]=(short)f2bf(y.x); afr[5]=(short)f2bf(y.y); afr[6]=(short)f2bf(y.z); afr[7]=(short)f2bf(y.w);
    }
    const f32x4 zacc = {0.f, 0.f, 0.f, 0.f};
    float bs0 = 3.4e38f, bs1 = 3.4e38f, bs2 = 3.4e38f, bs3 = 3.4e38f;
#pragma unroll 1
    for (int nt = 0; nt < NTILES; ++nt) {
        bf16x8 b = *(const bf16x8*)(bfrag + nt * 512 + lane * 8);
        f32x4 d = __builtin_amdgcn_mfma_f32_16x16x32_bf16(afr, b, zacc, 0, 0, 0);
        float e2c = e2[nt * 16 + col16];
        bs0 = fminf(bs0, __builtin_fmaf(-2.f, d[0], e2c));
        bs1 = fminf(bs1, __builtin_fmaf(-2.f, d[1], e2c));
        bs2 = fminf(bs2, __builtin_fmaf(-2.f, d[2], e2c));
        bs3 = fminf(bs3, __builtin_fmaf(-2.f, d[3], e2c));
    }
#pragma unroll
    for (int m = 1; m < 16; m <<= 1) {
        bs0 = fminf(bs0, __shfl_xor(bs0, m));
        bs1 = fminf(bs1, __shfl_xor(bs1, m));
        bs2 = fminf(bs2, __shfl_xor(bs2, m));
        bs3 = fminf(bs3, __shfl_xor(bs3, m));
    }
    if (col16 == 0) {
        const size_t r = row0 + quad * 4;
        thr[r]     = bs0 + THRESH;
        thr[r + 1] = bs1 + THRESH;
        thr[r + 2] = bs2 + THRESH;
        thr[r + 3] = bs3 + THRESH;
        cnt[r] = 0; cnt[r + 1] = 0; cnt[r + 2] = 0; cnt[r + 3] = 0;
    }
}

// ---- K3: same sweep; qualifying (row,c) appended to cand[row][.] ----
__global__ __launch_bounds__(256) void vq_filter(
    const float* __restrict__ h,
    const float* __restrict__ e2,
    const unsigned short* __restrict__ bfrag,
    const float* __restrict__ thr,
    u32* __restrict__ cnt, u32* __restrict__ cand)
{
    const int wid   = (blockIdx.x * 256 + threadIdx.x) >> 6;
    const int lane  = threadIdx.x & 63;
    const int col16 = lane & 15;
    const int quad  = lane >> 4;
    const size_t row0 = (size_t)wid * 16;

    bf16x8 afr;
    {
        const float* ap = h + (row0 + col16) * DIM + quad * 8;
        float4 x = *(const float4*)ap, y = *(const float4*)(ap + 4);
        afr[0]=(short)f2bf(x.x); afr[1]=(short)f2bf(x.y); afr[2]=(short)f2bf(x.z); afr[3]=(short)f2bf(x.w);
        afr[4]=(short)f2bf(y.x); afr[5]=(short)f2bf(y.y); afr[6]=(short)f2bf(y.z); afr[7]=(short)f2bf(y.w);
    }
    // thresholds for this lane's 4 rows, preloaded
    const int rbase = (int)row0 + quad * 4;
    float t0 = thr[rbase], t1 = thr[rbase + 1], t2 = thr[rbase + 2], t3 = thr[rbase + 3];

    const f32x4 zacc = {0.f, 0.f, 0.f, 0.f};
#pragma unroll 1
    for (int nt = 0; nt < NTILES; ++nt) {
        bf16x8 b = *(const bf16x8*)(bfrag + nt * 512 + lane * 8);
        f32x4 d = __builtin_amdgcn_mfma_f32_16x16x32_bf16(afr, b, zacc, 0, 0, 0);
        float e2c = e2[nt * 16 + col16];
        const u32 cc = nt * 16 + col16;
        float s0 = __builtin_fmaf(-2.f, d[0], e2c);
        float s1 = __builtin_fmaf(-2.f, d[1], e2c);
        float s2 = __builtin_fmaf(-2.f, d[2], e2c);
        float s3 = __builtin_fmaf(-2.f, d[3], e2c);
        if (s0 <= t0) { u32 sl = atomicAdd(&cnt[rbase],     1u); if (sl < MAXC) cand[(size_t)rbase * MAXC + sl] = cc; }
        if (s1 <= t1) { u32 sl = atomicAdd(&cnt[rbase + 1], 1u); if (sl < MAXC) cand[((size_t)rbase + 1) * MAXC + sl] = cc; }
        if (s2 <= t2) { u32 sl = atomicAdd(&cnt[rbase + 2], 1u); if (sl < MAXC) cand[((size_t)rbase + 2) * MAXC + sl] = cc; }
        if (s3 <= t3) { u32 sl = atomicAdd(&cnt[rbase + 3], 1u); if (sl < MAXC) cand[((size_t)rbase + 3) * MAXC + sl] = cc; }
    }
}

// ---- K4: exact recheck of listed candidates + epilogue ----
__global__ __launch_bounds__(256) void vq_exact(
    const float* __restrict__ h, const float* __restrict__ emb,
    const float* __restrict__ e2,
    const u32* __restrict__ cnt, const u32* __restrict__ cand,
    float* __restrict__ out_q, float* __restrict__ out_idx,
    float* __restrict__ out_loss)
{
#pragma clang fp contract(off)
    const int v = blockIdx.x * 256 + threadIdx.x;
    const float* f = h + (size_t)v * DIM;
    float fr[DIM];
#pragma unroll
    for (int i = 0; i < DIM; i += 4) {
        float4 x = *(const float4*)(f + i);
        fr[i] = x.x; fr[i + 1] = x.y; fr[i + 2] = x.z; fr[i + 3] = x.w;
    }
    const float f2 = norm2_np(fr);
    const u32 n = cnt[v];
    u64 best = ~0ull;
    if (n >= 1 && n <= MAXC) {
        for (u32 j = 0; j < n; ++j) {
            const u32 c = cand[(size_t)v * MAXC + j];
            const float* ep = emb + (size_t)c * DIM;
            float a = 0.f;
#pragma unroll
            for (int k = 0; k < DIM; ++k) a = __builtin_fmaf(fr[k], ep[k], a);  // BLAS chain
            float dd = (f2 + e2[c]) - (2.0f * a);     // exact numpy formula
            u64 key = ((u64)enc_f32(dd) << 32) | c;
            if (key < best) best = key;
        }
    } else {  // overflow / empty (effectively never): full exact scan
        for (u32 c = 0; c < EMB_N; ++c) {
            const float* ep = emb + (size_t)c * DIM;
            float a = 0.f;
#pragma unroll
            for (int k = 0; k < DIM; ++k) a = __builtin_fmaf(fr[k], ep[k], a);
            float dd = (f2 + e2[c]) - (2.0f * a);
            u64 key = ((u64)enc_f32(dd) << 32) | c;
            if (key < best) best = key;
        }
    }
    const int bidx = (int)(best & 0xFFFFFFFFu);

    const float* q = emb + (size_t)bidx * DIM;
    float ps = 0.f;
#pragma unroll
    for (int i = 0; i < DIM; i += 4) {
        float4 qx; qx.x = q[i]; qx.y = q[i+1]; qx.z = q[i+2]; qx.w = q[i+3];
        float dx = qx.x - fr[i], dy = qx.y - fr[i+1], dz = qx.z - fr[i+2], dw = qx.w - fr[i+3];
        ps += dx * dx; ps += dy * dy; ps += dz * dz; ps += dw * dw;
        float4 o;
        o.x = fr[i]     + (qx.x - fr[i]);
        o.y = fr[i + 1] + (qx.y - fr[i + 1]);
        o.z = fr[i + 2] + (qx.z - fr[i + 2]);
        o.w = fr[i + 3] + (qx.w - fr[i + 3]);
        *(float4*)(out_q + (size_t)v * DIM + i) = o;
    }
    float m = ps * (1.0f / DIM);
    out_idx[v]  = (float)bidx;
    out_loss[v] = m * 0.1f + m * 0.1f;
}

// ---------- fallback (R3-style) if workspace too small ----------
__global__ void e2_kernel(const float* __restrict__ emb, float* __restrict__ e2) {
#pragma clang fp contract(off)
    int c = blockIdx.x * blockDim.x + threadIdx.x;
    if (c >= EMB_N) return;
    const float* e = emb + (size_t)c * DIM;
    float tmp[DIM];
#pragma unroll
    for (int i = 0; i < DIM; ++i) tmp[i] = e[i];
    e2[c] = norm2_np(tmp);
}

__global__ __launch_bounds__(256) void vq_kernel(
    const float* __restrict__ h, const float* __restrict__ emb,
    const float* __restrict__ e2, float* __restrict__ out_q,
    float* __restrict__ out_idx, float* __restrict__ out_loss)
{
#pragma clang fp contract(off)
    const int v = blockIdx.x * blockDim.x + threadIdx.x;
    const float* f = h + (size_t)v * DIM;
    float fr[DIM];
#pragma unroll
    for (int i = 0; i < DIM; i += 4) {
        float4 x = *(const float4*)(f + i);
        fr[i] = x.x; fr[i + 1] = x.y; fr[i + 2] = x.z; fr[i + 3] = x.w;
    }
    const float f2 = norm2_np(fr);
    float best = 3.4e38f; int bidx = 0;
#pragma unroll 1
    for (int c = 0; c < EMB_N; ++c) {
        const float* e = emb + (size_t)c * DIM;
        float a0 = 0.f;
#pragma unroll
        for (int k = 0; k < DIM; ++k) a0 = __builtin_fmaf(fr[k], e[k], a0);
        float d0 = (f2 + e2[c]) - (2.0f * a0);
        if (d0 < best) { best = d0; bidx = c; }
    }
    const float* q = emb + (size_t)bidx * DIM;
    float ps = 0.f;
#pragma unroll
    for (int i = 0; i < DIM; i += 4) {
        float4 qx; qx.x = q[i]; qx.y = q[i+1]; qx.z = q[i+2]; qx.w = q[i+3];
        float dx = qx.x - fr[i], dy = qx.y - fr[i+1], dz = qx.z - fr[i+2], dw = qx.w - fr[i+3];
        ps += dx * dx; ps += dy * dy; ps += dz * dz; ps += dw * dw;
        float4 o;
        o.x = fr[i] + (qx.x - fr[i]); o.y = fr[i+1] + (qx.y - fr[i+1]);
        o.z = fr[i+2] + (qx.z - fr[i+2]); o.w = fr[i+3] + (qx.w - fr[i+3]);
        *(float4*)(out_q + (size_t)v * DIM + i) = o;
    }
    float m = ps * (1.0f / DIM);
    out_idx[v]  = (float)bidx;
    out_loss[v] = m * 0.1f + m * 0.1f;
}

extern "C" void kernel_launch(void* const* d_in, const int* in_sizes, int n_in,
                              void* d_out, int out_size, void* d_ws, size_t ws_size,
                              hipStream_t stream) {
    const float* h   = (const float*)d_in[0];
    const float* emb = (const float*)d_in[1];
    float* out = (float*)d_out;
    float* out_q    = out;                               // 4194304
    float* out_idx  = out + (size_t)NVEC * DIM;          // 131072
    float* out_loss = out + (size_t)NVEC * DIM + NVEC;   // 131072

    // ws layout
    float*          e2    = (float*)d_ws;                                   // 4 KB
    unsigned short* bfrag = (unsigned short*)((char*)d_ws + 4096);          // 64 KB
    float*          thr   = (float*)((char*)d_ws + 4096 + 65536);           // 512 KB
    u32*            cnt   = (u32*)((char*)d_ws + 4096 + 65536 + 524288);    // 512 KB
    u32*            cand  = (u32*)((char*)d_ws + 4096 + 65536 + 1048576);   // 4 MB
    const size_t need = 4096 + 65536 + 1048576 + (size_t)NVEC * MAXC * sizeof(u32);

    if (ws_size >= need) {
        prep_kernel<<<16, 256, 0, stream>>>(emb, e2, bfrag);
        vq_thresh<<<2048, 256, 0, stream>>>(h, e2, bfrag, thr, cnt);
        vq_filter<<<2048, 256, 0, stream>>>(h, e2, bfrag, thr, cnt, cand);
        vq_exact<<<NVEC / 256, 256, 0, stream>>>(h, emb, e2, cnt, cand,
                                                 out_q, out_idx, out_loss);
    } else {
        e2_kernel<<<EMB_N / 256, 256, 0, stream>>>(emb, e2);
        vq_kernel<<<NVEC / 256, 256, 0, stream>>>(h, emb, e2, out_q, out_idx, out_loss);
    }
}

// Round 8
// 141.207 us; speedup vs baseline: 6.1703x; 4.0094x over previous
//
#include <hip/hip_runtime.h>

// VQ-VAE quantizer: h (256,512,32) fp32, embeddings (1024,32) fp32.
// d_out (fp32): quantized_st [4194304] | indices [131072] | loss [131072]
//
// R8: bf16-MFMA certified filter with PER-ROW certified threshold + fused
// two-sweep scan + ballot-compacted candidate lists + n==1 shortcut.
//   K1 prep:  e2 (numpy pairwise) + bf16 B-frag table (MFMA lane layout)
//   K2 scan:  32 rows/wave. sweep1: approx min per row (MFMA). threshold
//             T_row = 2^-16 * Sum|f_k| + 1e-4  (certified: bf16 2*dot error
//             <= 2^-17*Sum|f_k| per candidate, np rounding <= ~1e-5).
//             sweep2: recompute (bit-identical), ballot-compact qualifiers
//             into cand[row][0..MAXC), exact count in cnt[row]. No atomics.
//   K3 exact: n==1 -> answer is cand[0] (no math). n in [2,MAXC] -> bit-exact
//             numpy recheck (pairwise ||f||^2, sequential fmaf dot,
//             fl(fl(f2+e2)-2dot)), u64 key enc(d)<<32|c -> first-occurrence
//             argmin. n>MAXC (P~1e-7/row) -> wave-uniform full exact scan.
//             + epilogue (quantized_st, idx, loss).
// History: R3 270 -> R4 240 -> R5 193 -> R6 871 (fused divergent recheck) ->
//          R7 566 (T too loose: serial fallback storm; split sweeps 2x bfrag).

#define EMB_N 1024
#define DIM 32
#define NVEC (256 * 512)
#define NTILES (EMB_N / 16)
#define MAXC 8

typedef unsigned long long u64;
typedef unsigned int u32;
typedef unsigned short ushortT;
typedef __attribute__((ext_vector_type(8))) short bf16x8;
typedef __attribute__((ext_vector_type(4))) float f32x4;

__device__ __forceinline__ u32 enc_f32(float x) {
    u32 u = __float_as_uint(x);
    return (u & 0x80000000u) ? ~u : (u | 0x80000000u);  // monotone order-preserving
}
__device__ __forceinline__ ushortT f2bf(float f) {  // RNE fp32->bf16
    u32 u = __float_as_uint(f);
    return (ushortT)((u + 0x7FFFu + ((u >> 16) & 1u)) >> 16);
}

// numpy pairwise ||x||^2, n=32: 8 accumulators stride 8, fixed combine tree
__device__ __forceinline__ float norm2_np(const float* fr) {
    float sq[DIM];
#pragma unroll
    for (int i = 0; i < DIM; ++i) sq[i] = fr[i] * fr[i];
    float r[8];
#pragma unroll
    for (int j = 0; j < 8; ++j)
        r[j] = ((sq[j] + sq[j + 8]) + sq[j + 16]) + sq[j + 24];
    return ((r[0] + r[1]) + (r[2] + r[3])) + ((r[4] + r[5]) + (r[6] + r[7]));
}

// ---- K1: e2 + bf16 B-frag table. frag(nt,lane,j) = bf16(emb[nt*16+(lane&15)][(lane>>4)*8+j])
__global__ __launch_bounds__(256) void prep_kernel(
    const float* __restrict__ emb, float* __restrict__ e2,
    ushortT* __restrict__ bfrag)
{
#pragma clang fp contract(off)
    const int t = blockIdx.x * 256 + threadIdx.x;    // 0..4095
    const int l = t & 63;
    const int row = ((t >> 6) << 4) + (l & 15);
    const int k0 = (l >> 4) * 8;
    const float* ep = emb + (size_t)row * DIM + k0;
    ushortT* dst = bfrag + (size_t)t * 8;
#pragma unroll
    for (int j = 0; j < 8; ++j) dst[j] = f2bf(ep[j]);
    if (t < EMB_N) {
        const float* e = emb + (size_t)t * DIM;
        float tmp[DIM];
#pragma unroll
        for (int i = 0; i < DIM; ++i) tmp[i] = e[i];
        e2[t] = norm2_np(tmp);
    }
}

// ---- K2: fused sweep1 (min) + sweep2 (filter). 1 wave = 32 rows. ----
__global__ __launch_bounds__(256) void vq_scan(
    const float* __restrict__ h,
    const float* __restrict__ e2,
    const ushortT* __restrict__ bfrag,
    u32* __restrict__ cnt, u32* __restrict__ cand)
{
#pragma clang fp contract(off)
    const int wid   = (blockIdx.x * 256 + threadIdx.x) >> 6;  // 0..4095
    const int lane  = threadIdx.x & 63;
    const int col16 = lane & 15;
    const int quad  = lane >> 4;
    const size_t row0 = (size_t)wid * 32;

    // A-frags for rows row0+col16 (tile0), row0+16+col16 (tile1); fp32 abs-sums
    bf16x8 afr0, afr1;
    float sa0, sa1;
    {
        const float* ap = h + (row0 + col16) * DIM + quad * 8;
        float4 x = *(const float4*)ap, y = *(const float4*)(ap + 4);
        afr0[0]=(short)f2bf(x.x); afr0[1]=(short)f2bf(x.y); afr0[2]=(short)f2bf(x.z); afr0[3]=(short)f2bf(x.w);
        afr0[4]=(short)f2bf(y.x); afr0[5]=(short)f2bf(y.y); afr0[6]=(short)f2bf(y.z); afr0[7]=(short)f2bf(y.w);
        sa0 = fabsf(x.x)+fabsf(x.y)+fabsf(x.z)+fabsf(x.w)+fabsf(y.x)+fabsf(y.y)+fabsf(y.z)+fabsf(y.w);
        const float* bp = ap + 16 * DIM;
        float4 u = *(const float4*)bp, v = *(const float4*)(bp + 4);
        afr1[0]=(short)f2bf(u.x); afr1[1]=(short)f2bf(u.y); afr1[2]=(short)f2bf(u.z); afr1[3]=(short)f2bf(u.w);
        afr1[4]=(short)f2bf(v.x); afr1[5]=(short)f2bf(v.y); afr1[6]=(short)f2bf(v.z); afr1[7]=(short)f2bf(v.w);
        sa1 = fabsf(u.x)+fabsf(u.y)+fabsf(u.z)+fabsf(u.w)+fabsf(v.x)+fabsf(v.y)+fabsf(v.z)+fabsf(v.w);
    }
    // total Sum|f| per row: reduce the 4 k-chunks (held across quads)
    sa0 += __shfl_xor(sa0, 16); sa0 += __shfl_xor(sa0, 32);
    sa1 += __shfl_xor(sa1, 16); sa1 += __shfl_xor(sa1, 32);
    // now lane L holds Sum|f| of row row0+(L&15) in sa0, row0+16+(L&15) in sa1

    const f32x4 zacc = {0.f, 0.f, 0.f, 0.f};

    // ---- sweep 1: approx min per slot (slot i: tile i>>2, reg i&3) ----
    float bs[8];
#pragma unroll
    for (int i = 0; i < 8; ++i) bs[i] = 3.4e38f;
#pragma unroll 2
    for (int nt = 0; nt < NTILES; ++nt) {
        bf16x8 b = *(const bf16x8*)(bfrag + nt * 512 + lane * 8);
        f32x4 d0 = __builtin_amdgcn_mfma_f32_16x16x32_bf16(afr0, b, zacc, 0, 0, 0);
        f32x4 d1 = __builtin_amdgcn_mfma_f32_16x16x32_bf16(afr1, b, zacc, 0, 0, 0);
        float e2c = e2[nt * 16 + col16];
#pragma unroll
        for (int r = 0; r < 4; ++r) {
            bs[r]     = fminf(bs[r],     __builtin_fmaf(-2.f, d0[r], e2c));
            bs[4 + r] = fminf(bs[4 + r], __builtin_fmaf(-2.f, d1[r], e2c));
        }
    }
#pragma unroll
    for (int m = 1; m < 16; m <<= 1)
#pragma unroll
        for (int i = 0; i < 8; ++i) bs[i] = fminf(bs[i], __shfl_xor(bs[i], m));

    // per-row certified threshold: thr = min + 2^-16*Sum|f| + 1e-4
    float thr[8];
#pragma unroll
    for (int i = 0; i < 8; ++i) {
        float sar = __shfl((i >> 2) ? sa1 : sa0, quad * 4 + (i & 3));
        thr[i] = bs[i] + __builtin_fmaf(sar, 0x1p-16f, 1.0e-4f);
    }

    // ---- sweep 2: recompute (bit-identical), ballot-compact qualifiers ----
    u32 cl[8];
#pragma unroll
    for (int i = 0; i < 8; ++i) cl[i] = 0;
    const u32 colmask = (1u << col16) - 1u;
#pragma unroll 2
    for (int nt = 0; nt < NTILES; ++nt) {
        bf16x8 b = *(const bf16x8*)(bfrag + nt * 512 + lane * 8);
        f32x4 d0 = __builtin_amdgcn_mfma_f32_16x16x32_bf16(afr0, b, zacc, 0, 0, 0);
        f32x4 d1 = __builtin_amdgcn_mfma_f32_16x16x32_bf16(afr1, b, zacc, 0, 0, 0);
        float e2c = e2[nt * 16 + col16];
        const u32 cc = nt * 16 + col16;
        bool q[8];
        bool any = false;
#pragma unroll
        for (int i = 0; i < 8; ++i) {
            float s = __builtin_fmaf(-2.f, ((i >> 2) ? d1[i & 3] : d0[i & 3]), e2c);
            q[i] = (s <= thr[i]);
            any |= q[i];
        }
        if (__ballot(any)) {
#pragma unroll
            for (int i = 0; i < 8; ++i) {
                u64 mball = __ballot(q[i]);
                u32 my = (u32)((mball >> (quad * 16)) & 0xFFFFu);
                if (q[i]) {
                    u32 slot = cl[i] + (u32)__popc(my & colmask);
                    const size_t row = row0 + ((i >> 2) << 4) + quad * 4 + (i & 3);
                    if (slot < MAXC) cand[row * MAXC + slot] = cc;
                }
                cl[i] += (u32)__popc(my);
            }
        }
    }
    if (col16 == 0) {
#pragma unroll
        for (int i = 0; i < 8; ++i) {
            const size_t row = row0 + ((i >> 2) << 4) + quad * 4 + (i & 3);
            cnt[row] = cl[i];
        }
    }
}

// ---- K3: exact recheck of listed candidates + epilogue ----
__global__ __launch_bounds__(256) void vq_exact(
    const float* __restrict__ h, const float* __restrict__ emb,
    const float* __restrict__ e2,
    const u32* __restrict__ cnt, const u32* __restrict__ cand,
    float* __restrict__ out_q, float* __restrict__ out_idx,
    float* __restrict__ out_loss)
{
#pragma clang fp contract(off)
    const int v = blockIdx.x * 256 + threadIdx.x;
    const float* f = h + (size_t)v * DIM;
    float fr[DIM];
#pragma unroll
    for (int i = 0; i < DIM; i += 4) {
        float4 x = *(const float4*)(f + i);
        fr[i] = x.x; fr[i + 1] = x.y; fr[i + 2] = x.z; fr[i + 3] = x.w;
    }
    const u32 n = cnt[v];
    int bidx;
    if (n == 1) {
        bidx = (int)cand[(size_t)v * MAXC];       // sole certified qualifier
    } else if (n <= MAXC) {
        const float f2 = norm2_np(fr);
        u64 best = ~0ull;
        for (u32 j = 0; j < n; ++j) {
            const u32 c = cand[(size_t)v * MAXC + j];
            const float* ep = emb + (size_t)c * DIM;
            float a = 0.f;
#pragma unroll
            for (int k = 0; k < DIM; ++k) a = __builtin_fmaf(fr[k], ep[k], a);  // BLAS chain
            float dd = (f2 + e2[c]) - (2.0f * a);     // exact numpy formula
            u64 key = ((u64)enc_f32(dd) << 32) | c;
            if (key < best) best = key;
        }
        bidx = (int)(best & 0xFFFFFFFFu);
    } else {  // overflow (P ~ 1e-7/row): wave-uniform full exact scan
        const float f2 = norm2_np(fr);
        u64 best = ~0ull;
        for (u32 c = 0; c < EMB_N; ++c) {
            const float* ep = emb + (size_t)c * DIM;   // uniform -> s_load
            float a = 0.f;
#pragma unroll
            for (int k = 0; k < DIM; ++k) a = __builtin_fmaf(fr[k], ep[k], a);
            float dd = (f2 + e2[c]) - (2.0f * a);
            u64 key = ((u64)enc_f32(dd) << 32) | c;
            if (key < best) best = key;
        }
        bidx = (int)(best & 0xFFFFFFFFu);
    }

    const float* q = emb + (size_t)bidx * DIM;
    float ps = 0.f;
#pragma unroll
    for (int i = 0; i < DIM; i += 4) {
        float4 qx; qx.x = q[i]; qx.y = q[i+1]; qx.z = q[i+2]; qx.w = q[i+3];
        float dx = qx.x - fr[i], dy = qx.y - fr[i+1], dz = qx.z - fr[i+2], dw = qx.w - fr[i+3];
        ps += dx * dx; ps += dy * dy; ps += dz * dz; ps += dw * dw;
        float4 o;
        o.x = fr[i]     + (qx.x - fr[i]);
        o.y = fr[i + 1] + (qx.y - fr[i + 1]);
        o.z = fr[i + 2] + (qx.z - fr[i + 2]);
        o.w = fr[i + 3] + (qx.w - fr[i + 3]);
        *(float4*)(out_q + (size_t)v * DIM + i) = o;
    }
    float m = ps * (1.0f / DIM);
    out_idx[v]  = (float)bidx;
    out_loss[v] = m * 0.1f + m * 0.1f;
}

// ---------- fallback (R3-style) if workspace too small ----------
__global__ void e2_kernel(const float* __restrict__ emb, float* __restrict__ e2) {
#pragma clang fp contract(off)
    int c = blockIdx.x * blockDim.x + threadIdx.x;
    if (c >= EMB_N) return;
    const float* e = emb + (size_t)c * DIM;
    float tmp[DIM];
#pragma unroll
    for (int i = 0; i < DIM; ++i) tmp[i] = e[i];
    e2[c] = norm2_np(tmp);
}

__global__ __launch_bounds__(256) void vq_kernel(
    const float* __restrict__ h, const float* __restrict__ emb,
    const float* __restrict__ e2, float* __restrict__ out_q,
    float* __restrict__ out_idx, float* __restrict__ out_loss)
{
#pragma clang fp contract(off)
    const int v = blockIdx.x * blockDim.x + threadIdx.x;
    const float* f = h + (size_t)v * DIM;
    float fr[DIM];
#pragma unroll
    for (int i = 0; i < DIM; i += 4) {
        float4 x = *(const float4*)(f + i);
        fr[i] = x.x; fr[i + 1] = x.y; fr[i + 2] = x.z; fr[i + 3] = x.w;
    }
    const float f2 = norm2_np(fr);
    float best = 3.4e38f; int bidx = 0;
#pragma unroll 1
    for (int c = 0; c < EMB_N; ++c) {
        const float* e = emb + (size_t)c * DIM;
        float a0 = 0.f;
#pragma unroll
        for (int k = 0; k < DIM; ++k) a0 = __builtin_fmaf(fr[k], e[k], a0);
        float d0 = (f2 + e2[c]) - (2.0f * a0);
        if (d0 < best) { best = d0; bidx = c; }
    }
    const float* q = emb + (size_t)bidx * DIM;
    float ps = 0.f;
#pragma unroll
    for (int i = 0; i < DIM; i += 4) {
        float4 qx; qx.x = q[i]; qx.y = q[i+1]; qx.z = q[i+2]; qx.w = q[i+3];
        float dx = qx.x - fr[i], dy = qx.y - fr[i+1], dz = qx.z - fr[i+2], dw = qx.w - fr[i+3];
        ps += dx * dx; ps += dy * dy; ps += dz * dz; ps += dw * dw;
        float4 o;
        o.x = fr[i] + (qx.x - fr[i]); o.y = fr[i+1] + (qx.y - fr[i+1]);
        o.z = fr[i+2] + (qx.z - fr[i+2]); o.w = fr[i+3] + (qx.w - fr[i+3]);
        *(float4*)(out_q + (size_t)v * DIM + i) = o;
    }
    float m = ps * (1.0f / DIM);
    out_idx[v]  = (float)bidx;
    out_loss[v] = m * 0.1f + m * 0.1f;
}

extern "C" void kernel_launch(void* const* d_in, const int* in_sizes, int n_in,
                              void* d_out, int out_size, void* d_ws, size_t ws_size,
                              hipStream_t stream) {
    const float* h   = (const float*)d_in[0];
    const float* emb = (const float*)d_in[1];
    float* out = (float*)d_out;
    float* out_q    = out;                               // 4194304
    float* out_idx  = out + (size_t)NVEC * DIM;          // 131072
    float* out_loss = out + (size_t)NVEC * DIM + NVEC;   // 131072

    // ws layout: e2 4KB | bfrag 64KB | cnt 512KB | cand 4MB  (~4.6 MB)
    float*   e2    = (float*)d_ws;
    ushortT* bfrag = (ushortT*)((char*)d_ws + 4096);
    u32*     cnt   = (u32*)((char*)d_ws + 4096 + 65536);
    u32*     cand  = (u32*)((char*)d_ws + 4096 + 65536 + (size_t)NVEC * sizeof(u32));
    const size_t need = 4096 + 65536 + (size_t)NVEC * sizeof(u32)
                      + (size_t)NVEC * MAXC * sizeof(u32);

    if (ws_size >= need) {
        prep_kernel<<<16, 256, 0, stream>>>(emb, e2, bfrag);
        vq_scan<<<1024, 256, 0, stream>>>(h, e2, bfrag, cnt, cand);
        vq_exact<<<NVEC / 256, 256, 0, stream>>>(h, emb, e2, cnt, cand,
                                                 out_q, out_idx, out_loss);
    } else {
        e2_kernel<<<EMB_N / 256, 256, 0, stream>>>(emb, e2);
        vq_kernel<<<NVEC / 256, 256, 0, stream>>>(h, emb, e2, out_q, out_idx, out_loss);
    }
}

// Round 9
// 131.229 us; speedup vs baseline: 6.6395x; 1.0760x over previous
//
#include <hip/hip_runtime.h>

// VQ-VAE quantizer: h (256,512,32) fp32, embeddings (1024,32) fp32.
// d_out (fp32): quantized_st [4194304] | indices [131072] | loss [131072]
//
// R9: single fused scan kernel (R8's separate vq_exact ran at 2 waves/SIMD —
// pure latency, ~55us). bf16-MFMA certified filter; qualifiers appended to
// wave-private LDS; tail does exact recheck + epilogue in the same waves,
// hidden behind other waves' sweeps (16 waves/CU).
//   prep:   e2 (numpy pairwise) + bf16 B-frag table (MFMA lane layout)
//   scan:   32 rows/wave. sweep1: approx min/row (MFMA), certified threshold
//           T_row = 2^-16*Sum|f_k| + 1e-4 (bf16 2*dot err <= 2^-17*Sum|f_k|).
//           sweep2: recompute (bit-identical), LDS-append qualifiers.
//           tail:   overflow rows (P~1e-7) -> wave-cooperative exact scan;
//                   owner lane per row: n==1 -> done; n in [2,8] -> bit-exact
//                   numpy recheck (pairwise ||f||^2, sequential fmaf dot,
//                   fl(fl(f2+e2)-2dot)), u64 key enc(d)<<32|c (first-occurrence
//                   argmin); epilogue (quantized_st, idx, loss).
// History: R3 270 -> R4 240 -> R5 193 -> R6 871 -> R7 566 -> R8 141
//          (scan 66us @ VALU 58%; exact ~55us latency-bound).

#define EMB_N 1024
#define DIM 32
#define NVEC (256 * 512)
#define NTILES (EMB_N / 16)
#define MAXC 8

typedef unsigned long long u64;
typedef unsigned int u32;
typedef unsigned short ushortT;
typedef __attribute__((ext_vector_type(8))) short bf16x8;
typedef __attribute__((ext_vector_type(4))) float f32x4;

__device__ __forceinline__ u32 enc_f32(float x) {
    u32 u = __float_as_uint(x);
    return (u & 0x80000000u) ? ~u : (u | 0x80000000u);  // monotone order-preserving
}
__device__ __forceinline__ ushortT f2bf(float f) {  // RNE fp32->bf16
    u32 u = __float_as_uint(f);
    return (ushortT)((u + 0x7FFFu + ((u >> 16) & 1u)) >> 16);
}
__device__ __forceinline__ u64 shflx_u64(u64 x, int m) {
    int lo = __shfl_xor((int)(u32)x, m);
    int hi = __shfl_xor((int)(x >> 32), m);
    return ((u64)(u32)hi << 32) | (u32)lo;
}

// numpy pairwise ||x||^2, n=32: 8 accumulators stride 8, fixed combine tree
__device__ __forceinline__ float norm2_np(const float* fr) {
    float sq[DIM];
#pragma unroll
    for (int i = 0; i < DIM; ++i) sq[i] = fr[i] * fr[i];
    float r[8];
#pragma unroll
    for (int j = 0; j < 8; ++j)
        r[j] = ((sq[j] + sq[j + 8]) + sq[j + 16]) + sq[j + 24];
    return ((r[0] + r[1]) + (r[2] + r[3])) + ((r[4] + r[5]) + (r[6] + r[7]));
}

// ---- prep: e2 + bf16 B-frag table. frag(nt,lane,j) = bf16(emb[nt*16+(lane&15)][(lane>>4)*8+j])
__global__ __launch_bounds__(256) void prep_kernel(
    const float* __restrict__ emb, float* __restrict__ e2,
    ushortT* __restrict__ bfrag)
{
#pragma clang fp contract(off)
    const int t = blockIdx.x * 256 + threadIdx.x;    // 0..4095
    const int l = t & 63;
    const int row = ((t >> 6) << 4) + (l & 15);
    const int k0 = (l >> 4) * 8;
    const float* ep = emb + (size_t)row * DIM + k0;
    ushortT* dst = bfrag + (size_t)t * 8;
#pragma unroll
    for (int j = 0; j < 8; ++j) dst[j] = f2bf(ep[j]);
    if (t < EMB_N) {
        const float* e = emb + (size_t)t * DIM;
        float tmp[DIM];
#pragma unroll
        for (int i = 0; i < DIM; ++i) tmp[i] = e[i];
        e2[t] = norm2_np(tmp);
    }
}

// ---- fused scan + recheck + epilogue. 1 wave = 32 rows. ----
__global__ __launch_bounds__(256) void vq_scan(
    const float* __restrict__ h,
    const float* __restrict__ emb,
    const float* __restrict__ e2,
    const ushortT* __restrict__ bfrag,
    float* __restrict__ out_q, float* __restrict__ out_idx,
    float* __restrict__ out_loss)
{
#pragma clang fp contract(off)
    __shared__ u32 lds_cnt[4][32];
    __shared__ u32 lds_cand[4][32 * MAXC];

    const int wslot = threadIdx.x >> 6;
    const int wid   = (blockIdx.x * 256 + threadIdx.x) >> 6;  // 0..4095
    const int lane  = threadIdx.x & 63;
    const int col16 = lane & 15;
    const int quad  = lane >> 4;
    const size_t row0 = (size_t)wid * 32;

    u32* cnt  = lds_cnt[wslot];    // wave-private
    u32* cand = lds_cand[wslot];
    if (lane < 32) cnt[lane] = 0;

    // A-frags for rows row0+col16 (tile0), row0+16+col16 (tile1); fp32 abs-sums
    bf16x8 afr0, afr1;
    float sa0, sa1;
    {
        const float* ap = h + (row0 + col16) * DIM + quad * 8;
        float4 x = *(const float4*)ap, y = *(const float4*)(ap + 4);
        afr0[0]=(short)f2bf(x.x); afr0[1]=(short)f2bf(x.y); afr0[2]=(short)f2bf(x.z); afr0[3]=(short)f2bf(x.w);
        afr0[4]=(short)f2bf(y.x); afr0[5]=(short)f2bf(y.y); afr0[6]=(short)f2bf(y.z); afr0[7]=(short)f2bf(y.w);
        sa0 = fabsf(x.x)+fabsf(x.y)+fabsf(x.z)+fabsf(x.w)+fabsf(y.x)+fabsf(y.y)+fabsf(y.z)+fabsf(y.w);
        const float* bp = ap + 16 * DIM;
        float4 u = *(const float4*)bp, v = *(const float4*)(bp + 4);
        afr1[0]=(short)f2bf(u.x); afr1[1]=(short)f2bf(u.y); afr1[2]=(short)f2bf(u.z); afr1[3]=(short)f2bf(u.w);
        afr1[4]=(short)f2bf(v.x); afr1[5]=(short)f2bf(v.y); afr1[6]=(short)f2bf(v.z); afr1[7]=(short)f2bf(v.w);
        sa1 = fabsf(u.x)+fabsf(u.y)+fabsf(u.z)+fabsf(u.w)+fabsf(v.x)+fabsf(v.y)+fabsf(v.z)+fabsf(v.w);
    }
    sa0 += __shfl_xor(sa0, 16); sa0 += __shfl_xor(sa0, 32);
    sa1 += __shfl_xor(sa1, 16); sa1 += __shfl_xor(sa1, 32);

    const f32x4 zacc = {0.f, 0.f, 0.f, 0.f};

    // ---- sweep 1: approx min per slot (slot i: tile i>>2, reg i&3) ----
    float bs[8];
#pragma unroll
    for (int i = 0; i < 8; ++i) bs[i] = 3.4e38f;
#pragma unroll 2
    for (int nt = 0; nt < NTILES; ++nt) {
        bf16x8 b = *(const bf16x8*)(bfrag + nt * 512 + lane * 8);
        f32x4 d0 = __builtin_amdgcn_mfma_f32_16x16x32_bf16(afr0, b, zacc, 0, 0, 0);
        f32x4 d1 = __builtin_amdgcn_mfma_f32_16x16x32_bf16(afr1, b, zacc, 0, 0, 0);
        float e2c = e2[nt * 16 + col16];
#pragma unroll
        for (int r = 0; r < 4; ++r) {
            bs[r]     = fminf(bs[r],     __builtin_fmaf(-2.f, d0[r], e2c));
            bs[4 + r] = fminf(bs[4 + r], __builtin_fmaf(-2.f, d1[r], e2c));
        }
    }
#pragma unroll
    for (int m = 1; m < 16; m <<= 1)
#pragma unroll
        for (int i = 0; i < 8; ++i) bs[i] = fminf(bs[i], __shfl_xor(bs[i], m));

    // per-row certified threshold: thr = min + 2^-16*Sum|f| + 1e-4
    float thr[8];
#pragma unroll
    for (int i = 0; i < 8; ++i) {
        float sar = __shfl((i >> 2) ? sa1 : sa0, quad * 4 + (i & 3));
        thr[i] = bs[i] + __builtin_fmaf(sar, 0x1p-16f, 1.0e-4f);
    }

    // ---- sweep 2: recompute (bit-identical), LDS-append qualifiers ----
#pragma unroll 2
    for (int nt = 0; nt < NTILES; ++nt) {
        bf16x8 b = *(const bf16x8*)(bfrag + nt * 512 + lane * 8);
        f32x4 d0 = __builtin_amdgcn_mfma_f32_16x16x32_bf16(afr0, b, zacc, 0, 0, 0);
        f32x4 d1 = __builtin_amdgcn_mfma_f32_16x16x32_bf16(afr1, b, zacc, 0, 0, 0);
        float e2c = e2[nt * 16 + col16];
        const u32 cc = nt * 16 + col16;
        bool q[8];
        bool any = false;
#pragma unroll
        for (int i = 0; i < 8; ++i) {
            float s = __builtin_fmaf(-2.f, ((i >> 2) ? d1[i & 3] : d0[i & 3]), e2c);
            q[i] = (s <= thr[i]);
            any |= q[i];
        }
        if (__ballot(any)) {
#pragma unroll
            for (int i = 0; i < 8; ++i) {
                if (__ballot(q[i])) {
                    if (q[i]) {
                        const int rloc = ((i >> 2) << 4) + quad * 4 + (i & 3);
                        u32 slot = atomicAdd(&cnt[rloc], 1u);
                        if (slot < MAXC) cand[rloc * MAXC + slot] = cc;
                    }
                }
            }
        }
    }

    // ---- tail A: overflowed rows (P~1e-7) -> wave-cooperative exact scan ----
    u64 ovf = __ballot((lane < 32) && (cnt[lane & 31] > MAXC));
    while (ovf) {
        const int r = (int)(__ffsll((unsigned long long)ovf) - 1);
        ovf &= ovf - 1;
        const float* fp = h + (row0 + r) * DIM;   // wave-uniform row
        float fu[DIM];
#pragma unroll
        for (int i = 0; i < DIM; i += 4) {
            float4 x = *(const float4*)(fp + i);
            fu[i] = x.x; fu[i + 1] = x.y; fu[i + 2] = x.z; fu[i + 3] = x.w;
        }
        const float f2 = norm2_np(fu);
        u64 bk = ~0ull;
        for (int c = lane; c < EMB_N; c += 64) {
            const float* ep = emb + (size_t)c * DIM;
            float a = 0.f;
#pragma unroll
            for (int k = 0; k < DIM; ++k) a = __builtin_fmaf(fu[k], ep[k], a);
            float dd = (f2 + e2[c]) - (2.0f * a);
            u64 key = ((u64)enc_f32(dd) << 32) | (u32)c;
            if (key < bk) bk = key;
        }
#pragma unroll
        for (int m = 1; m < 64; m <<= 1) {
            u64 o = shflx_u64(bk, m);
            if (o < bk) bk = o;
        }
        if (lane == 0) { cand[r * MAXC] = (u32)bk; cnt[r] = 1; }
    }

    // ---- tail B: owner lane per row -> recheck + epilogue ----
    if (lane < 32) {
        const int row = (int)row0 + lane;
        const u32 n = cnt[lane];
        const float* f = h + (size_t)row * DIM;
        float fr[DIM];
#pragma unroll
        for (int i = 0; i < DIM; i += 4) {
            float4 x = *(const float4*)(f + i);
            fr[i] = x.x; fr[i + 1] = x.y; fr[i + 2] = x.z; fr[i + 3] = x.w;
        }
        int bidx;
        if (n == 1) {
            bidx = (int)cand[lane * MAXC];       // sole certified qualifier
        } else {
            const float f2 = norm2_np(fr);
            u64 best = ~0ull;
            for (u32 j = 0; j < n; ++j) {
                const u32 c = cand[lane * MAXC + j];
                const float* ep = emb + (size_t)c * DIM;
                float a = 0.f;
#pragma unroll
                for (int k = 0; k < DIM; ++k) a = __builtin_fmaf(fr[k], ep[k], a);  // BLAS chain
                float dd = (f2 + e2[c]) - (2.0f * a);     // exact numpy formula
                u64 key = ((u64)enc_f32(dd) << 32) | c;
                if (key < best) best = key;
            }
            bidx = (int)(best & 0xFFFFFFFFu);
        }

        const float* qv = emb + (size_t)bidx * DIM;
        float ps = 0.f;
#pragma unroll
        for (int i = 0; i < DIM; i += 4) {
            float4 qx; qx.x = qv[i]; qx.y = qv[i+1]; qx.z = qv[i+2]; qx.w = qv[i+3];
            float dx = qx.x - fr[i], dy = qx.y - fr[i+1], dz = qx.z - fr[i+2], dw = qx.w - fr[i+3];
            ps += dx * dx; ps += dy * dy; ps += dz * dz; ps += dw * dw;
            float4 o;
            o.x = fr[i]     + (qx.x - fr[i]);
            o.y = fr[i + 1] + (qx.y - fr[i + 1]);
            o.z = fr[i + 2] + (qx.z - fr[i + 2]);
            o.w = fr[i + 3] + (qx.w - fr[i + 3]);
            *(float4*)(out_q + (size_t)row * DIM + i) = o;
        }
        float m = ps * (1.0f / DIM);
        out_idx[row]  = (float)bidx;
        out_loss[row] = m * 0.1f + m * 0.1f;
    }
}

// ---------- fallback (R3-style) if workspace too small ----------
__global__ void e2_kernel(const float* __restrict__ emb, float* __restrict__ e2) {
#pragma clang fp contract(off)
    int c = blockIdx.x * blockDim.x + threadIdx.x;
    if (c >= EMB_N) return;
    const float* e = emb + (size_t)c * DIM;
    float tmp[DIM];
#pragma unroll
    for (int i = 0; i < DIM; ++i) tmp[i] = e[i];
    e2[c] = norm2_np(tmp);
}

__global__ __launch_bounds__(256) void vq_kernel(
    const float* __restrict__ h, const float* __restrict__ emb,
    const float* __restrict__ e2, float* __restrict__ out_q,
    float* __restrict__ out_idx, float* __restrict__ out_loss)
{
#pragma clang fp contract(off)
    const int v = blockIdx.x * blockDim.x + threadIdx.x;
    const float* f = h + (size_t)v * DIM;
    float fr[DIM];
#pragma unroll
    for (int i = 0; i < DIM; i += 4) {
        float4 x = *(const float4*)(f + i);
        fr[i] = x.x; fr[i + 1] = x.y; fr[i + 2] = x.z; fr[i + 3] = x.w;
    }
    const float f2 = norm2_np(fr);
    float best = 3.4e38f; int bidx = 0;
#pragma unroll 1
    for (int c = 0; c < EMB_N; ++c) {
        const float* e = emb + (size_t)c * DIM;
        float a0 = 0.f;
#pragma unroll
        for (int k = 0; k < DIM; ++k) a0 = __builtin_fmaf(fr[k], e[k], a0);
        float d0 = (f2 + e2[c]) - (2.0f * a0);
        if (d0 < best) { best = d0; bidx = c; }
    }
    const float* q = emb + (size_t)bidx * DIM;
    float ps = 0.f;
#pragma unroll
    for (int i = 0; i < DIM; i += 4) {
        float4 qx; qx.x = q[i]; qx.y = q[i+1]; qx.z = q[i+2]; qx.w = q[i+3];
        float dx = qx.x - fr[i], dy = qx.y - fr[i+1], dz = qx.z - fr[i+2], dw = qx.w - fr[i+3];
        ps += dx * dx; ps += dy * dy; ps += dz * dz; ps += dw * dw;
        float4 o;
        o.x = fr[i] + (qx.x - fr[i]); o.y = fr[i+1] + (qx.y - fr[i+1]);
        o.z = fr[i+2] + (qx.z - fr[i+2]); o.w = fr[i+3] + (qx.w - fr[i+3]);
        *(float4*)(out_q + (size_t)v * DIM + i) = o;
    }
    float m = ps * (1.0f / DIM);
    out_idx[v]  = (float)bidx;
    out_loss[v] = m * 0.1f + m * 0.1f;
}

extern "C" void kernel_launch(void* const* d_in, const int* in_sizes, int n_in,
                              void* d_out, int out_size, void* d_ws, size_t ws_size,
                              hipStream_t stream) {
    const float* h   = (const float*)d_in[0];
    const float* emb = (const float*)d_in[1];
    float* out = (float*)d_out;
    float* out_q    = out;                               // 4194304
    float* out_idx  = out + (size_t)NVEC * DIM;          // 131072
    float* out_loss = out + (size_t)NVEC * DIM + NVEC;   // 131072

    // ws layout: e2 4KB | bfrag 64KB
    float*   e2    = (float*)d_ws;
    ushortT* bfrag = (ushortT*)((char*)d_ws + 4096);
    const size_t need = 4096 + (size_t)NTILES * 512 * sizeof(ushortT);

    if (ws_size >= need) {
        prep_kernel<<<16, 256, 0, stream>>>(emb, e2, bfrag);
        vq_scan<<<1024, 256, 0, stream>>>(h, emb, e2, bfrag, out_q, out_idx, out_loss);
    } else {
        e2_kernel<<<EMB_N / 256, 256, 0, stream>>>(emb, e2);
        vq_kernel<<<NVEC / 256, 256, 0, stream>>>(h, emb, e2, out_q, out_idx, out_loss);
    }
}